// Round 1
// baseline (754.968 us; speedup 1.0000x reference)
//
#include <hip/hip_runtime.h>
#include <hip/hip_bf16.h>

typedef unsigned short u16;
typedef __attribute__((ext_vector_type(8))) short short8;
typedef __attribute__((ext_vector_type(4))) float f32x4;

#define EPSV 1e-5f
#define ENC_NINF 0x007FFFFFu

__device__ __forceinline__ float bf2f(u16 u) {
    union { unsigned int i; float f; } v; v.i = ((unsigned int)u) << 16; return v.f;
}
__device__ __forceinline__ u16 f2bf(float f) {
    union { float f; unsigned int i; } v; v.f = f;
    unsigned int x = v.i;
    return (u16)((x + 0x7FFFu + ((x >> 16) & 1u)) >> 16);   // RNE
}
__device__ __forceinline__ unsigned int encbf(u16 u) {
    unsigned int f = ((unsigned int)u) << 16;
    return (f & 0x80000000u) ? ~f : (f | 0x80000000u);
}
__device__ __forceinline__ float dec(unsigned int u) {
    union { float f; unsigned int uu; } v;
    v.uu = (u & 0x80000000u) ? (u & 0x7FFFFFFFu) : ~u;
    return v.f;
}

// async 16B global -> LDS (per-lane source ok; LDS dest = uniform base + lane*16)
__device__ __forceinline__ void async16(const u16* g, u16* l) {
    __builtin_amdgcn_global_load_lds((const __attribute__((address_space(1))) void*)g,
                                     (__attribute__((address_space(3))) void*)l,
                                     16, 0, 0);
}

__global__ __launch_bounds__(256) void k_fillf(float* __restrict__ o, int n, float val)
{
    int i = blockIdx.x * 256 + threadIdx.x;
    if (i < n) o[i] = val;
}

// ---- adaptive repack: float tensors -> bf16 blob; choice -> clean int32 ----
// also initializes the fg_u/out_u encoded-max buffers (folded k_initu)
struct Ptrs { const void* p[17]; int off[18]; int chN; };

__global__ __launch_bounds__(256) void k_repack(Ptrs P, const void* __restrict__ chSrc,
                                                int* __restrict__ chi, u16* __restrict__ rp,
                                                unsigned int* __restrict__ initp, int nU)
{
    const unsigned int* probe = (const unsigned int*)P.p[9];   // w3, |x| << 2
    int cnt = 0;
#pragma unroll
    for (int i = 0; i < 64; ++i) {
        unsigned int lo = probe[i] & 0xFFFFu;
        if (((lo >> 7) & 0xFFu) >= 0x80u) ++cnt;
    }
    const bool is_f32 = (cnt > 8);

    const unsigned int* cp = (const unsigned int*)chSrc;
    int z = 0; unsigned int mx = 0;
    for (int i = 0; i < 1024; ++i) {
        unsigned int w = cp[i];
        z += (w == 0u);
        mx = (w > mx) ? w : mx;
    }
    const int chMode = (mx >= 64u) ? 2 : ((z > 300) ? 1 : 0);  // 2=f32, 1=i64, 0=i32

    const int stride = gridDim.x * 256;
    const int gid0 = blockIdx.x * 256 + threadIdx.x;

    const int totalF = P.off[17];
    for (int g = gid0; g < totalF; g += stride) {
        int t = 0;
        while (g >= P.off[t + 1]) ++t;
        int off = g - P.off[t];
        u16 v;
        if (is_f32) v = f2bf(((const float*)P.p[t])[off]);
        else        v = ((const u16*)P.p[t])[off];
        rp[g] = v;
    }
    for (int i = gid0; i < P.chN; i += stride) {
        int v;
        if (chMode == 1)      v = (int)((const long long*)chSrc)[i];
        else if (chMode == 2) v = (int)((const float*)chSrc)[i];
        else                  v = ((const int*)chSrc)[i];
        chi[i] = v & 63;
    }
    for (int i = gid0; i < nU; i += stride) initp[i] = ENC_NINF;
}

// ---- counting sort per batch: points ordered by cluster ----
__global__ __launch_bounds__(256) void k_sort(const int* __restrict__ chi,
                                              int* __restrict__ schoice,
                                              int* __restrict__ perm)
{
    __shared__ int hist[64];
    __shared__ int base[64];
    const int b = blockIdx.x, tid = threadIdx.x;
    if (tid < 64) hist[tid] = 0;
    __syncthreads();
    const int o = b << 13;
    for (int i = tid; i < 8192; i += 256) atomicAdd(&hist[chi[o + i]], 1);
    __syncthreads();
    if (tid == 0) {
        int s = 0;
        for (int k = 0; k < 64; ++k) { base[k] = s; s += hist[k]; }
    }
    __syncthreads();
    for (int i = tid; i < 8192; i += 256) {
        int k = chi[o + i];
        int pos = atomicAdd(&base[k], 1);
        schoice[o + pos] = k;
        perm[o + pos] = o + i;
    }
}

// ---- G1 (NT=2): feat = (relu(bn1(xyz.w1^T+b1))) . w2^T + b2, seg-max fused ----
__global__ __launch_bounds__(256, 2) void g1_feat(
    const u16* __restrict__ xyz, const u16* __restrict__ w1, const u16* __restrict__ b1,
    const u16* __restrict__ g1v, const u16* __restrict__ bb1,
    const u16* __restrict__ m1, const u16* __restrict__ v1,
    const u16* __restrict__ w2, const u16* __restrict__ b2,
    const int* __restrict__ schoice, const int* __restrict__ perm,
    u16* __restrict__ feat, unsigned int* __restrict__ fg_u)
{
    __shared__ __align__(16) u16 Bs[256 * 128];      // 64 KB: both w2 halves
    __shared__ unsigned int lred[8 * 256];           // 8 KB (nk <= 8 fast path)
    __shared__ float4 pw[128];
    __shared__ float xs[128], ys[128], zs[128];
    __shared__ int chs[128];
    const int tid = threadIdx.x, lane = tid & 63, wave = tid >> 6;
    const int wm = (wave & 1) << 6, wn = (wave >> 1) << 6;
    const int m0 = blockIdx.x << 7;
    if (tid < 128) {
        float s = bf2f(g1v[tid]) * rsqrtf(bf2f(v1[tid]) + EPSV);
        float4 w;
        w.x = bf2f(w1[tid * 3 + 0]) * s;
        w.y = bf2f(w1[tid * 3 + 1]) * s;
        w.z = bf2f(w1[tid * 3 + 2]) * s;
        w.w = (bf2f(b1[tid]) - bf2f(m1[tid])) * s + bf2f(bb1[tid]);
        pw[tid] = w;
        const u16* p = xyz + (size_t)perm[m0 + tid] * 3;
        xs[tid] = bf2f(p[0]); ys[tid] = bf2f(p[1]); zs[tid] = bf2f(p[2]);
        chs[tid] = schoice[m0 + tid];
    }
    const int q = lane >> 4, mr = lane & 15;
    f32x4 acc[2][4][4] = {};
#pragma unroll
    for (int i = 0; i < 16; ++i) {
        int id = (i << 8) + tid, row = id >> 4, cc = id & 15;
        async16(w2 + (size_t)row * 128 + ((cc ^ (row & 15)) << 3), &Bs[id << 3]);
    }
    __syncthreads();
    const int kmin = chs[0], nk = chs[127] - kmin + 1;
    const bool useL = (nk <= 8);
    if (useL) for (int i = tid; i < (nk << 8); i += 256) lred[i] = ENC_NINF;
#pragma unroll
    for (int kk = 0; kk < 4; ++kk) {
        const int lc = kk * 4 + q;
        float4 wv[8];
#pragma unroll
        for (int j = 0; j < 8; ++j) wv[j] = pw[kk * 32 + q * 8 + j];
        short8 af[4];
#pragma unroll
        for (int mi = 0; mi < 4; ++mi) {
            int row = wm + mi * 16 + mr;
            float x = xs[row], y = ys[row], z = zs[row];
#pragma unroll
            for (int j = 0; j < 8; ++j) {
                float val = fmaf(x, wv[j].x, fmaf(y, wv[j].y, fmaf(z, wv[j].z, wv[j].w)));
                af[mi][j] = (short)f2bf(fmaxf(val, 0.0f));
            }
        }
#pragma unroll
        for (int h = 0; h < 2; ++h) {
            short8 bfr[4];
#pragma unroll
            for (int ni = 0; ni < 4; ++ni) {
                int r = (h << 7) + wn + ni * 16 + mr;
                bfr[ni] = *(const short8*)&Bs[r * 128 + ((lc ^ (r & 15)) << 3)];
            }
#pragma unroll
            for (int mi = 0; mi < 4; ++mi)
#pragma unroll
                for (int ni = 0; ni < 4; ++ni)
                    acc[h][mi][ni] = __builtin_amdgcn_mfma_f32_16x16x32_bf16(af[mi], bfr[ni], acc[h][mi][ni], 0, 0, 0);
        }
    }
    __syncthreads();
    const int colb = lane & 15;
    const int bl = m0 >> 13;
    unsigned int* db = fg_u + (size_t)(bl << 6) * 256;
#pragma unroll
    for (int h = 0; h < 2; ++h)
#pragma unroll
        for (int ni = 0; ni < 4; ++ni) {
            int n = (h << 7) + wn + (ni << 4) + colb;
            float bv = bf2f(b2[n]);
#pragma unroll
            for (int mi = 0; mi < 4; ++mi) {
                int curk = -1; unsigned int run = 0;
#pragma unroll
                for (int r = 0; r < 4; ++r) {
                    int rr = wm + (mi << 4) + (q << 2) + r;
                    u16 vb = f2bf(acc[h][mi][ni][r] + bv);
                    feat[(size_t)(m0 + rr) * 256 + n] = vb;
                    unsigned int e = encbf(vb);
                    int k = chs[rr];
                    if (k != curk) {
                        if (curk >= 0) {
                            if (useL) atomicMax(&lred[((curk - kmin) << 8) + n], run);
                            else      atomicMax(&db[curk * 256 + n], run);
                        }
                        curk = k; run = e;
                    } else run = run > e ? run : e;
                }
                if (useL) atomicMax(&lred[((curk - kmin) << 8) + n], run);
                else      atomicMax(&db[curk * 256 + n], run);
            }
        }
    if (useL) {
        __syncthreads();
        for (int i = tid; i < (nk << 8); i += 256) {
            unsigned int v = lred[i];
            if (v != ENC_NINF) atomicMax(&db[(kmin + (i >> 8)) * 256 + (i & 255)], v);
        }
    }
}

// ---- G34: fused second_conv + out-proj + seg-max ----
// out = relu(bn2([fg_pts|feat].w3^T + b3)) . w4^T + b4 -> seg-max into out_u.
// 512 threads (8 waves, 2M x 4N). Per block: 128 rows.
// Phase A (per 256-col half): h2 half via MFMA (acc 64 f/lane), bn2+relu -> bf16 LDS H.
// Phase B: out_acc(96 f/lane) += H . w4_half^T. h2 never touches global memory.
__global__ __launch_bounds__(512, 2) void g34_out(
    const int* __restrict__ schoice, const u16* __restrict__ feat,
    const u16* __restrict__ fg, const u16* __restrict__ w3, const u16* __restrict__ b3,
    const u16* __restrict__ g2, const u16* __restrict__ bb2,
    const u16* __restrict__ m2, const u16* __restrict__ v2,
    const u16* __restrict__ w4, const u16* __restrict__ b4,
    unsigned int* __restrict__ out_u)
{
    __shared__ __align__(16) u16 uni[24576];   // 48 KB: As(16K)+Bs(32K)  |  Bs2(48K)
    __shared__ __align__(16) u16 H[32768];     // 64 KB: h2 half 128x256 swizzled | lred
    __shared__ int chs[128];
    u16* As  = uni;
    u16* Bs  = uni + 8192;
    u16* Bs2 = uni;
    const int tid = threadIdx.x, lane = tid & 63, wave = tid >> 6;
    const int q = lane >> 4, mr = lane & 15, colb = lane & 15;
    const int wm2  = (wave & 1) << 6;           // M offset (2 waves in M)
    const int wn4  = ((wave >> 1) & 3) << 6;    // phase-A N offset within 256 half
    const int wn96 = (wave >> 1) * 96;          // phase-B N offset (384 total)
    const int m0 = blockIdx.x << 7;
    const int c = tid & 7, rb = tid >> 3;       // staging coords (64 rows / 8 chunks)
    if (tid < 128) chs[tid] = schoice[m0 + tid];
    const u16* arow[2]; const u16* frow[2];
#pragma unroll
    for (int i = 0; i < 2; ++i) {
        int pt = m0 + rb + (i << 6);
        int b = pt >> 13;
        arow[i] = fg + (((b << 6) + schoice[pt]) << 8);
        frow[i] = feat + ((size_t)pt << 8);
    }
    f32x4 acc_b[4][6] = {};
    for (int nh = 0; nh < 2; ++nh) {
        // ---- phase A: h2[:, nh*256 : +256] = [fg|feat] . w3_half^T ----
        f32x4 acc_a[4][4] = {};
        for (int k0 = 0; k0 < 512; k0 += 64) {
            __syncthreads();
#pragma unroll
            for (int i = 0; i < 4; ++i) {       // w3 half: 256 rows x 64 k
                int id = (i << 9) + tid, row = id >> 3, cc = id & 7;
                async16(w3 + (size_t)((nh << 8) + row) * 512 + k0 + ((cc ^ (row & 7)) << 3),
                        &Bs[id << 3]);
            }
#pragma unroll
            for (int i = 0; i < 2; ++i) {       // A: 128 rows x 64 k from fg|feat
                int r = rb + (i << 6);
                int col = k0 + ((c ^ (r & 7)) << 3);
                const u16* src = (k0 < 256) ? (arow[i] + col) : (frow[i] + (col - 256));
                async16(src, &As[(((i << 9) + tid) << 3)]);
            }
            __syncthreads();
#pragma unroll
            for (int kk = 0; kk < 2; ++kk) {
                const int lc = (kk << 2) + q;
                short8 af[4], bfr[4];
#pragma unroll
                for (int mi = 0; mi < 4; ++mi) {
                    int r = wm2 + (mi << 4) + mr;
                    af[mi] = *(const short8*)&As[r * 64 + ((lc ^ (r & 7)) << 3)];
                }
#pragma unroll
                for (int ni = 0; ni < 4; ++ni) {
                    int r = wn4 + (ni << 4) + mr;
                    bfr[ni] = *(const short8*)&Bs[r * 64 + ((lc ^ (r & 7)) << 3)];
                }
#pragma unroll
                for (int mi = 0; mi < 4; ++mi)
#pragma unroll
                    for (int ni = 0; ni < 4; ++ni)
                        acc_a[mi][ni] = __builtin_amdgcn_mfma_f32_16x16x32_bf16(af[mi], bfr[ni], acc_a[mi][ni], 0, 0, 0);
            }
        }
        // ---- bn2 + relu -> H (swizzled bf16, A-operand layout) ----
        __syncthreads();                         // nh=1: prior phase-B H reads done
#pragma unroll
        for (int ni = 0; ni < 4; ++ni) {
            int n = (nh << 8) + wn4 + (ni << 4) + colb;
            float s = bf2f(g2[n]) * rsqrtf(bf2f(v2[n]) + EPSV);
            float t = (bf2f(b3[n]) - bf2f(m2[n])) * s + bf2f(bb2[n]);
            int ck = wn4 + (ni << 4) + colb;
            int cchi = ck >> 3, clo = ck & 7;
#pragma unroll
            for (int mi = 0; mi < 4; ++mi)
#pragma unroll
                for (int r = 0; r < 4; ++r) {
                    int rr = wm2 + (mi << 4) + (q << 2) + r;
                    H[rr * 256 + ((cchi ^ (rr & 7)) << 3) + clo] =
                        f2bf(fmaxf(fmaf(acc_a[mi][ni][r], s, t), 0.0f));
                }
        }
        // ---- phase B: acc_b += H(128x256) . w4[:, nh*256+k]^T ----
        for (int k0 = 0; k0 < 256; k0 += 64) {
            __syncthreads();                     // first iter also fences H writes
#pragma unroll
            for (int i = 0; i < 6; ++i) {       // w4: 384 rows x 64 k
                int id = (i << 9) + tid, row = id >> 3, cc = id & 7;
                async16(w4 + (size_t)row * 512 + (nh << 8) + k0 + ((cc ^ (row & 7)) << 3),
                        &Bs2[id << 3]);
            }
            __syncthreads();
            const int cb = k0 >> 3;
#pragma unroll
            for (int kk = 0; kk < 2; ++kk) {
                const int lc = (kk << 2) + q;
                short8 af[4];
#pragma unroll
                for (int mi = 0; mi < 4; ++mi) {
                    int r = wm2 + (mi << 4) + mr;
                    af[mi] = *(const short8*)&H[r * 256 + ((cb + (lc ^ (r & 7))) << 3)];
                }
#pragma unroll
                for (int ni = 0; ni < 6; ++ni) {
                    int r = wn96 + (ni << 4) + mr;
                    short8 bfr = *(const short8*)&Bs2[r * 64 + ((lc ^ (r & 7)) << 3)];
#pragma unroll
                    for (int mi = 0; mi < 4; ++mi)
                        acc_b[mi][ni] = __builtin_amdgcn_mfma_f32_16x16x32_bf16(af[mi], bfr, acc_b[mi][ni], 0, 0, 0);
                }
            }
        }
    }
    // ---- fused seg-max epilogue ----
    __syncthreads();                             // all H reads done; reuse H as lred
    unsigned int* lred = (unsigned int*)H;
    const int kmin = chs[0], nk = chs[127] - kmin + 1;
    const bool useL = (nk <= 40);                // lred needs nk*384*4 <= 64KB
    const int bl = m0 >> 13;
    unsigned int* db = out_u + (size_t)(bl << 6) * 384;
    if (useL) for (int i = tid; i < nk * 384; i += 512) lred[i] = ENC_NINF;
    __syncthreads();
#pragma unroll
    for (int ni = 0; ni < 6; ++ni) {
        int nc = wn96 + (ni << 4) + colb;
        float bv = bf2f(b4[nc]);
#pragma unroll
        for (int mi = 0; mi < 4; ++mi) {
            int curk = -1; unsigned int run = 0;
#pragma unroll
            for (int r = 0; r < 4; ++r) {
                int rr = wm2 + (mi << 4) + (q << 2) + r;
                unsigned int e = encbf(f2bf(acc_b[mi][ni][r] + bv));
                int k = chs[rr];
                if (k != curk) {
                    if (curk >= 0) {
                        if (useL) atomicMax(&lred[(curk - kmin) * 384 + nc], run);
                        else      atomicMax(&db[curk * 384 + nc], run);
                    }
                    curk = k; run = e;
                } else run = run > e ? run : e;
            }
            if (useL) atomicMax(&lred[(curk - kmin) * 384 + nc], run);
            else      atomicMax(&db[curk * 384 + nc], run);
        }
    }
    if (useL) {
        __syncthreads();
        for (int i = tid; i < nk * 384; i += 512) {
            unsigned int v = lred[i];
            if (v != ENC_NINF) {
                int kq = i / 384;
                atomicMax(&db[(kmin + kq) * 384 + (i - kq * 384)], v);
            }
        }
    }
}

__global__ __launch_bounds__(256) void k_dec_bf(const unsigned int* __restrict__ u,
                                                u16* __restrict__ o, int n)
{
    int i = blockIdx.x * 256 + threadIdx.x;
    if (i < n) o[i] = f2bf(dec(u[i]));
}
__global__ __launch_bounds__(256) void k_dec_f32(const unsigned int* __restrict__ u,
                                                 float* __restrict__ o, int n)
{
    int i = blockIdx.x * 256 + threadIdx.x;
    if (i < n) o[i] = dec(u[i]);
}

extern "C" void kernel_launch(void* const* d_in, const int* in_sizes, int n_in,
                              void* d_out, int out_size, void* d_ws, size_t ws_size,
                              hipStream_t stream)
{
    float* out = (float*)d_out;
    if (n_in != 18) {
        k_fillf<<<dim3((out_size + 255) / 256), 256, 0, stream>>>(out, out_size, 1000.0f);
        return;
    }

    const int map[17] = {0, 2, 3, 4, 5, 6, 7, 8, 9, 10, 11, 12, 13, 14, 15, 16, 17};
    Ptrs P;
    P.off[0] = 0;
    for (int i = 0; i < 17; ++i) {
        P.p[i] = d_in[map[i]];
        P.off[i + 1] = P.off[i] + in_sizes[map[i]];
    }
    P.chN = in_sizes[1];

    char* ws = (char*)d_ws;
    int* chi = (int*)ws;
    const size_t chiB = ((size_t)P.chN * 4 + 255) & ~255ull;
    int* schoice = (int*)(ws + chiB);
    int* perm    = (int*)(ws + 2 * chiB);
    u16* rp = (u16*)(ws + 3 * chiB);
    const size_t rpB = ((size_t)P.off[17] * 2 + 255) & ~255ull;
    const size_t RPB = 3 * chiB + rpB;

    // fixed region: fg_u (32*64*256 u32) + out_u (32*64*384 u32) = 5,242,880 B
    unsigned int* fg_u_all  = (unsigned int*)(ws + RPB);
    unsigned int* out_u_all = fg_u_all + 32 * 64 * 256;
    const size_t UB = 5242880ull;
    const int nU = 32 * 64 * 640;

    k_repack<<<dim3(1024), 256, 0, stream>>>(P, d_in[1], chi, rp, fg_u_all, nU);
    k_sort<<<dim3(P.chN >> 13), 256, 0, stream>>>(chi, schoice, perm);

    const u16* xyz  = rp + P.off[0];
    const u16* w1   = rp + P.off[1];
    const u16* b1   = rp + P.off[2];
    const u16* bn1g = rp + P.off[3];
    const u16* bn1b = rp + P.off[4];
    const u16* bn1m = rp + P.off[5];
    const u16* bn1v = rp + P.off[6];
    const u16* w2   = rp + P.off[7];
    const u16* b2   = rp + P.off[8];
    const u16* w3   = rp + P.off[9];
    const u16* b3   = rp + P.off[10];
    const u16* bn2g = rp + P.off[11];
    const u16* bn2b = rp + P.off[12];
    const u16* bn2m = rp + P.off[13];
    const u16* bn2v = rp + P.off[14];
    const u16* w4   = rp + P.off[15];
    const u16* b4   = rp + P.off[16];

    // per-batch: feat 4,194,304 + fg 32,768 = 4,227,072  (h2 eliminated by fusion)
    const size_t PB = 4227072ull;
    int sb = 32;
    while (sb > 1 && RPB + UB + (size_t)sb * PB > ws_size) sb >>= 1;
    if (RPB + UB + PB > ws_size) {
        k_fillf<<<dim3((out_size + 255) / 256), 256, 0, stream>>>(out, out_size, 3000.0f);
        return;
    }
    const int ns = 32 / sb;

    char* wsb = ws + RPB + UB;
    const size_t featB = (size_t)sb * 8192 * 256 * 2;
    u16* feat = (u16*)(wsb);
    u16* fg   = (u16*)(wsb + featB);

    const int mblk = sb << 6;        // 128-row M-tiles per slice
    const int nfg = sb * 64 * 256;
    const int nou = sb * 64 * 384;
    for (int s = 0; s < ns; ++s) {
        const int b0 = s * sb;
        const int pt0 = b0 << 13;
        const int* sch_sl = schoice + pt0;
        const int* perm_sl = perm + pt0;
        unsigned int* fg_u  = fg_u_all + (size_t)b0 * 64 * 256;
        unsigned int* out_u = out_u_all + (size_t)b0 * 64 * 384;
        g1_feat<<<dim3(mblk), 256, 0, stream>>>(xyz, w1, b1, bn1g, bn1b, bn1m, bn1v,
                                                w2, b2, sch_sl, perm_sl, feat, fg_u);
        k_dec_bf<<<dim3((nfg + 255) / 256), 256, 0, stream>>>(fg_u, fg, nfg);
        g34_out<<<dim3(mblk), 512, 0, stream>>>(sch_sl, feat, fg, w3, b3,
                                                bn2g, bn2b, bn2m, bn2v, w4, b4, out_u);
        k_dec_f32<<<dim3((nou + 255) / 256), 256, 0, stream>>>(out_u,
                                                               out + ((size_t)b0 << 6) * 384, nou);
    }
}

// Round 2
// 745.637 us; speedup vs baseline: 1.0125x; 1.0125x over previous
//
#include <hip/hip_runtime.h>
#include <hip/hip_bf16.h>

typedef unsigned short u16;
typedef __attribute__((ext_vector_type(8))) short short8;
typedef __attribute__((ext_vector_type(4))) float f32x4;

#define EPSV 1e-5f
#define ENC_NINF 0x007FFFFFu

__device__ __forceinline__ float bf2f(u16 u) {
    union { unsigned int i; float f; } v; v.i = ((unsigned int)u) << 16; return v.f;
}
__device__ __forceinline__ u16 f2bf(float f) {
    union { float f; unsigned int i; } v; v.f = f;
    unsigned int x = v.i;
    return (u16)((x + 0x7FFFu + ((x >> 16) & 1u)) >> 16);   // RNE
}
__device__ __forceinline__ unsigned int encbf(u16 u) {
    unsigned int f = ((unsigned int)u) << 16;
    return (f & 0x80000000u) ? ~f : (f | 0x80000000u);
}
__device__ __forceinline__ float dec(unsigned int u) {
    union { float f; unsigned int uu; } v;
    v.uu = (u & 0x80000000u) ? (u & 0x7FFFFFFFu) : ~u;
    return v.f;
}

// async 16B global -> LDS (per-lane source ok; LDS dest = uniform base + lane*16)
__device__ __forceinline__ void async16(const u16* g, u16* l) {
    __builtin_amdgcn_global_load_lds((const __attribute__((address_space(1))) void*)g,
                                     (__attribute__((address_space(3))) void*)l,
                                     16, 0, 0);
}

__global__ __launch_bounds__(256) void k_fillf(float* __restrict__ o, int n, float val)
{
    int i = blockIdx.x * 256 + threadIdx.x;
    if (i < n) o[i] = val;
}

// ---- adaptive repack: float tensors -> bf16 blob; choice -> clean int32 ----
// also initializes the fg_u/out_u encoded-max buffers (folded k_initu)
struct Ptrs { const void* p[17]; int off[18]; int chN; };

__global__ __launch_bounds__(256) void k_repack(Ptrs P, const void* __restrict__ chSrc,
                                                int* __restrict__ chi, u16* __restrict__ rp,
                                                unsigned int* __restrict__ initp, int nU)
{
    const unsigned int* probe = (const unsigned int*)P.p[9];   // w3, |x| << 2
    int cnt = 0;
#pragma unroll
    for (int i = 0; i < 64; ++i) {
        unsigned int lo = probe[i] & 0xFFFFu;
        if (((lo >> 7) & 0xFFu) >= 0x80u) ++cnt;
    }
    const bool is_f32 = (cnt > 8);

    const unsigned int* cp = (const unsigned int*)chSrc;
    int z = 0; unsigned int mx = 0;
    for (int i = 0; i < 1024; ++i) {
        unsigned int w = cp[i];
        z += (w == 0u);
        mx = (w > mx) ? w : mx;
    }
    const int chMode = (mx >= 64u) ? 2 : ((z > 300) ? 1 : 0);  // 2=f32, 1=i64, 0=i32

    const int stride = gridDim.x * 256;
    const int gid0 = blockIdx.x * 256 + threadIdx.x;

    const int totalF = P.off[17];
    for (int g = gid0; g < totalF; g += stride) {
        int t = 0;
        while (g >= P.off[t + 1]) ++t;
        int off = g - P.off[t];
        u16 v;
        if (is_f32) v = f2bf(((const float*)P.p[t])[off]);
        else        v = ((const u16*)P.p[t])[off];
        rp[g] = v;
    }
    for (int i = gid0; i < P.chN; i += stride) {
        int v;
        if (chMode == 1)      v = (int)((const long long*)chSrc)[i];
        else if (chMode == 2) v = (int)((const float*)chSrc)[i];
        else                  v = ((const int*)chSrc)[i];
        chi[i] = v & 63;
    }
    for (int i = gid0; i < nU; i += stride) initp[i] = ENC_NINF;
}

// ---- counting sort per batch: points ordered by cluster ----
__global__ __launch_bounds__(256) void k_sort(const int* __restrict__ chi,
                                              int* __restrict__ schoice,
                                              int* __restrict__ perm)
{
    __shared__ int hist[64];
    __shared__ int base[64];
    const int b = blockIdx.x, tid = threadIdx.x;
    if (tid < 64) hist[tid] = 0;
    __syncthreads();
    const int o = b << 13;
    for (int i = tid; i < 8192; i += 256) atomicAdd(&hist[chi[o + i]], 1);
    __syncthreads();
    if (tid == 0) {
        int s = 0;
        for (int k = 0; k < 64; ++k) { base[k] = s; s += hist[k]; }
    }
    __syncthreads();
    for (int i = tid; i < 8192; i += 256) {
        int k = chi[o + i];
        int pos = atomicAdd(&base[k], 1);
        schoice[o + pos] = k;
        perm[o + pos] = o + i;
    }
}

// ---- G1 (NT=2): feat = (relu(bn1(xyz.w1^T+b1))) . w2^T + b2, seg-max fused ----
__global__ __launch_bounds__(256, 2) void g1_feat(
    const u16* __restrict__ xyz, const u16* __restrict__ w1, const u16* __restrict__ b1,
    const u16* __restrict__ g1v, const u16* __restrict__ bb1,
    const u16* __restrict__ m1, const u16* __restrict__ v1,
    const u16* __restrict__ w2, const u16* __restrict__ b2,
    const int* __restrict__ schoice, const int* __restrict__ perm,
    u16* __restrict__ feat, unsigned int* __restrict__ fg_u)
{
    __shared__ __align__(16) u16 Bs[256 * 128];      // 64 KB: both w2 halves
    __shared__ unsigned int lred[8 * 256];           // 8 KB (nk <= 8 fast path)
    __shared__ float4 pw[128];
    __shared__ float xs[128], ys[128], zs[128];
    __shared__ int chs[128];
    const int tid = threadIdx.x, lane = tid & 63, wave = tid >> 6;
    const int wm = (wave & 1) << 6, wn = (wave >> 1) << 6;
    const int m0 = blockIdx.x << 7;
    if (tid < 128) {
        float s = bf2f(g1v[tid]) * rsqrtf(bf2f(v1[tid]) + EPSV);
        float4 w;
        w.x = bf2f(w1[tid * 3 + 0]) * s;
        w.y = bf2f(w1[tid * 3 + 1]) * s;
        w.z = bf2f(w1[tid * 3 + 2]) * s;
        w.w = (bf2f(b1[tid]) - bf2f(m1[tid])) * s + bf2f(bb1[tid]);
        pw[tid] = w;
        const u16* p = xyz + (size_t)perm[m0 + tid] * 3;
        xs[tid] = bf2f(p[0]); ys[tid] = bf2f(p[1]); zs[tid] = bf2f(p[2]);
        chs[tid] = schoice[m0 + tid];
    }
    const int q = lane >> 4, mr = lane & 15;
    f32x4 acc[2][4][4] = {};
#pragma unroll
    for (int i = 0; i < 16; ++i) {
        int id = (i << 8) + tid, row = id >> 4, cc = id & 15;
        async16(w2 + (size_t)row * 128 + ((cc ^ (row & 15)) << 3), &Bs[id << 3]);
    }
    __syncthreads();
    const int kmin = chs[0], nk = chs[127] - kmin + 1;
    const bool useL = (nk <= 8);
    if (useL) for (int i = tid; i < (nk << 8); i += 256) lred[i] = ENC_NINF;
#pragma unroll
    for (int kk = 0; kk < 4; ++kk) {
        const int lc = kk * 4 + q;
        float4 wv[8];
#pragma unroll
        for (int j = 0; j < 8; ++j) wv[j] = pw[kk * 32 + q * 8 + j];
        short8 af[4];
#pragma unroll
        for (int mi = 0; mi < 4; ++mi) {
            int row = wm + mi * 16 + mr;
            float x = xs[row], y = ys[row], z = zs[row];
#pragma unroll
            for (int j = 0; j < 8; ++j) {
                float val = fmaf(x, wv[j].x, fmaf(y, wv[j].y, fmaf(z, wv[j].z, wv[j].w)));
                af[mi][j] = (short)f2bf(fmaxf(val, 0.0f));
            }
        }
#pragma unroll
        for (int h = 0; h < 2; ++h) {
            short8 bfr[4];
#pragma unroll
            for (int ni = 0; ni < 4; ++ni) {
                int r = (h << 7) + wn + ni * 16 + mr;
                bfr[ni] = *(const short8*)&Bs[r * 128 + ((lc ^ (r & 15)) << 3)];
            }
#pragma unroll
            for (int mi = 0; mi < 4; ++mi)
#pragma unroll
                for (int ni = 0; ni < 4; ++ni)
                    acc[h][mi][ni] = __builtin_amdgcn_mfma_f32_16x16x32_bf16(af[mi], bfr[ni], acc[h][mi][ni], 0, 0, 0);
        }
    }
    __syncthreads();
    const int colb = lane & 15;
    const int bl = m0 >> 13;
    unsigned int* db = fg_u + (size_t)(bl << 6) * 256;
#pragma unroll
    for (int h = 0; h < 2; ++h)
#pragma unroll
        for (int ni = 0; ni < 4; ++ni) {
            int n = (h << 7) + wn + (ni << 4) + colb;
            float bv = bf2f(b2[n]);
#pragma unroll
            for (int mi = 0; mi < 4; ++mi) {
                int curk = -1; unsigned int run = 0;
#pragma unroll
                for (int r = 0; r < 4; ++r) {
                    int rr = wm + (mi << 4) + (q << 2) + r;
                    u16 vb = f2bf(acc[h][mi][ni][r] + bv);
                    feat[(size_t)(m0 + rr) * 256 + n] = vb;
                    unsigned int e = encbf(vb);
                    int k = chs[rr];
                    if (k != curk) {
                        if (curk >= 0) {
                            if (useL) atomicMax(&lred[((curk - kmin) << 8) + n], run);
                            else      atomicMax(&db[curk * 256 + n], run);
                        }
                        curk = k; run = e;
                    } else run = run > e ? run : e;
                }
                if (useL) atomicMax(&lred[((curk - kmin) << 8) + n], run);
                else      atomicMax(&db[curk * 256 + n], run);
            }
        }
    if (useL) {
        __syncthreads();
        for (int i = tid; i < (nk << 8); i += 256) {
            unsigned int v = lred[i];
            if (v != ENC_NINF) atomicMax(&db[(kmin + (i >> 8)) * 256 + (i & 255)], v);
        }
    }
}

// ---- G34: fused second_conv + out-proj + seg-max ----
// out = relu(bn2([fg_pts|feat].w3^T + b3)) . w4^T + b4 -> seg-max into out_u.
// 1024 threads (16 waves, 2M x 8N). Per block: 128 rows.
// Phase A (per 256-col half): h2 half via MFMA (acc_a 32 f/lane), bn2+relu -> bf16 LDS H.
// Phase B: acc_b (48 f/lane) += H . w4_half^T. h2 never touches global memory.
// Register budget: acc_b 48 + acc_a 32 + af 16 + bfr 8 + addr ~20 = ~124 <= 128
// (16-wave block => 4 waves/SIMD mandatory => 128-reg cap; r1's 512-thread
//  version needed 160+ accum regs and spilled 170 MB to scratch).
__global__ __launch_bounds__(1024, 4) void g34_out(
    const int* __restrict__ schoice, const u16* __restrict__ feat,
    const u16* __restrict__ fg, const u16* __restrict__ w3, const u16* __restrict__ b3,
    const u16* __restrict__ g2, const u16* __restrict__ bb2,
    const u16* __restrict__ m2, const u16* __restrict__ v2,
    const u16* __restrict__ w4, const u16* __restrict__ b4,
    unsigned int* __restrict__ out_u)
{
    __shared__ __align__(16) u16 uni[24576];   // 48 KB: As(16K)+Bs(32K)  |  Bs2(48K)
    __shared__ __align__(16) u16 H[32768];     // 64 KB: h2 half 128x256 swizzled | lred
    __shared__ int chs[128];
    u16* As  = uni;
    u16* Bs  = uni + 8192;
    u16* Bs2 = uni;
    const int tid = threadIdx.x, lane = tid & 63, wave = tid >> 6;
    const int q = lane >> 4, mr = lane & 15, colb = lane & 15;
    const int wm  = (wave & 1) << 6;            // M offset (2 waves in M)
    const int wnA = (wave >> 1) << 5;           // phase-A N offset (8 x 32 cols)
    const int wnB = (wave >> 1) * 48;           // phase-B N offset (8 x 48 cols)
    const int m0 = blockIdx.x << 7;
    if (tid < 128) chs[tid] = schoice[m0 + tid];
    // per-thread A-staging source: row sr = tid>>3, chunk sc = tid&7 (1 chunk/thread)
    const int sr = tid >> 3, sc = tid & 7;
    const int sbb = (m0 + sr) >> 13;
    const u16* arow = fg + (((sbb << 6) + schoice[m0 + sr]) << 8);
    const u16* frow = feat + ((size_t)(m0 + sr) << 8);
    const int scol = (sc ^ (sr & 7)) << 3;
    f32x4 acc_b[4][3] = {};
    for (int nh = 0; nh < 2; ++nh) {
        // ---- phase A: h2[:, nh*256 : +256] = [fg|feat] . w3_half^T ----
        f32x4 acc_a[4][2] = {};
        for (int k0 = 0; k0 < 512; k0 += 64) {
            __syncthreads();
#pragma unroll
            for (int i = 0; i < 2; ++i) {       // w3 half: 256 rows x 64 k
                int id = (i << 10) + tid, row = id >> 3, cc = id & 7;
                async16(w3 + (size_t)((nh << 8) + row) * 512 + k0 + ((cc ^ (row & 7)) << 3),
                        &Bs[id << 3]);
            }
            {                                    // A: 128 rows x 64 k from fg|feat
                int col = k0 + scol;
                const u16* src = (k0 < 256) ? (arow + col) : (frow + (col - 256));
                async16(src, &As[tid << 3]);
            }
            __syncthreads();
#pragma unroll
            for (int kk = 0; kk < 2; ++kk) {
                const int lc = (kk << 2) + q;
                short8 af[4], bfr[2];
#pragma unroll
                for (int mi = 0; mi < 4; ++mi) {
                    int r = wm + (mi << 4) + mr;
                    af[mi] = *(const short8*)&As[r * 64 + ((lc ^ (r & 7)) << 3)];
                }
#pragma unroll
                for (int ni = 0; ni < 2; ++ni) {
                    int r = wnA + (ni << 4) + mr;
                    bfr[ni] = *(const short8*)&Bs[r * 64 + ((lc ^ (r & 7)) << 3)];
                }
#pragma unroll
                for (int mi = 0; mi < 4; ++mi)
#pragma unroll
                    for (int ni = 0; ni < 2; ++ni)
                        acc_a[mi][ni] = __builtin_amdgcn_mfma_f32_16x16x32_bf16(af[mi], bfr[ni], acc_a[mi][ni], 0, 0, 0);
            }
        }
        // ---- bn2 + relu -> H (swizzled bf16, A-operand layout) ----
        // safe: all waves passed the k0=0 barrier after their prior phase-B reads
#pragma unroll
        for (int ni = 0; ni < 2; ++ni) {
            int ck = wnA + (ni << 4) + colb;     // 0..255 within half
            int n = (nh << 8) + ck;
            float s = bf2f(g2[n]) * rsqrtf(bf2f(v2[n]) + EPSV);
            float t = (bf2f(b3[n]) - bf2f(m2[n])) * s + bf2f(bb2[n]);
            int cchi = ck >> 3, clo = ck & 7;
#pragma unroll
            for (int mi = 0; mi < 4; ++mi)
#pragma unroll
                for (int r = 0; r < 4; ++r) {
                    int rr = wm + (mi << 4) + (q << 2) + r;
                    H[rr * 256 + ((cchi ^ (rr & 7)) << 3) + clo] =
                        f2bf(fmaxf(fmaf(acc_a[mi][ni][r], s, t), 0.0f));
                }
        }
        // ---- phase B: acc_b += H(128x256) . w4[:, nh*256+k]^T ----
        for (int k0 = 0; k0 < 256; k0 += 64) {
            __syncthreads();                     // As/Bs reads done -> Bs2 may overwrite
#pragma unroll
            for (int i = 0; i < 3; ++i) {       // w4: 384 rows x 64 k
                int id = (i << 10) + tid, row = id >> 3, cc = id & 7;
                async16(w4 + (size_t)row * 512 + (nh << 8) + k0 + ((cc ^ (row & 7)) << 3),
                        &Bs2[id << 3]);
            }
            __syncthreads();                     // Bs2 ready; H writes visible
#pragma unroll
            for (int kk = 0; kk < 2; ++kk) {
                const int lc = (kk << 2) + q;
                short8 af[4];
#pragma unroll
                for (int mi = 0; mi < 4; ++mi) {
                    int r = wm + (mi << 4) + mr;
                    int hc = (kk << 2) + q;      // chunk within this 64-k group
                    af[mi] = *(const short8*)&H[r * 256 + (((k0 >> 3) + (hc ^ (r & 7))) << 3)];
                }
#pragma unroll
                for (int ni = 0; ni < 3; ++ni) {
                    int r = wnB + (ni << 4) + mr;
                    short8 bfr = *(const short8*)&Bs2[r * 64 + ((lc ^ (r & 7)) << 3)];
#pragma unroll
                    for (int mi = 0; mi < 4; ++mi)
                        acc_b[mi][ni] = __builtin_amdgcn_mfma_f32_16x16x32_bf16(af[mi], bfr, acc_b[mi][ni], 0, 0, 0);
                }
            }
        }
    }
    // ---- fused seg-max epilogue ----
    __syncthreads();                             // all H reads done; reuse H as lred
    unsigned int* lred = (unsigned int*)H;
    const int kmin = chs[0], nk = chs[127] - kmin + 1;
    const bool useL = (nk <= 40);                // lred needs nk*384*4 <= 64KB
    const int bl = m0 >> 13;
    unsigned int* db = out_u + (size_t)(bl << 6) * 384;
    if (useL) for (int i = tid; i < nk * 384; i += 1024) lred[i] = ENC_NINF;
    __syncthreads();
#pragma unroll
    for (int ni = 0; ni < 3; ++ni) {
        int nc = wnB + (ni << 4) + colb;
        float bv = bf2f(b4[nc]);
#pragma unroll
        for (int mi = 0; mi < 4; ++mi) {
            int curk = -1; unsigned int run = 0;
#pragma unroll
            for (int r = 0; r < 4; ++r) {
                int rr = wm + (mi << 4) + (q << 2) + r;
                unsigned int e = encbf(f2bf(acc_b[mi][ni][r] + bv));
                int k = chs[rr];
                if (k != curk) {
                    if (curk >= 0) {
                        if (useL) atomicMax(&lred[(curk - kmin) * 384 + nc], run);
                        else      atomicMax(&db[curk * 384 + nc], run);
                    }
                    curk = k; run = e;
                } else run = run > e ? run : e;
            }
            if (useL) atomicMax(&lred[(curk - kmin) * 384 + nc], run);
            else      atomicMax(&db[curk * 384 + nc], run);
        }
    }
    if (useL) {
        __syncthreads();
        for (int i = tid; i < nk * 384; i += 1024) {
            unsigned int v = lred[i];
            if (v != ENC_NINF) {
                int kq = i / 384;
                atomicMax(&db[(kmin + kq) * 384 + (i - kq * 384)], v);
            }
        }
    }
}

__global__ __launch_bounds__(256) void k_dec_bf(const unsigned int* __restrict__ u,
                                                u16* __restrict__ o, int n)
{
    int i = blockIdx.x * 256 + threadIdx.x;
    if (i < n) o[i] = f2bf(dec(u[i]));
}
__global__ __launch_bounds__(256) void k_dec_f32(const unsigned int* __restrict__ u,
                                                 float* __restrict__ o, int n)
{
    int i = blockIdx.x * 256 + threadIdx.x;
    if (i < n) o[i] = dec(u[i]);
}

extern "C" void kernel_launch(void* const* d_in, const int* in_sizes, int n_in,
                              void* d_out, int out_size, void* d_ws, size_t ws_size,
                              hipStream_t stream)
{
    float* out = (float*)d_out;
    if (n_in != 18) {
        k_fillf<<<dim3((out_size + 255) / 256), 256, 0, stream>>>(out, out_size, 1000.0f);
        return;
    }

    const int map[17] = {0, 2, 3, 4, 5, 6, 7, 8, 9, 10, 11, 12, 13, 14, 15, 16, 17};
    Ptrs P;
    P.off[0] = 0;
    for (int i = 0; i < 17; ++i) {
        P.p[i] = d_in[map[i]];
        P.off[i + 1] = P.off[i] + in_sizes[map[i]];
    }
    P.chN = in_sizes[1];

    char* ws = (char*)d_ws;
    int* chi = (int*)ws;
    const size_t chiB = ((size_t)P.chN * 4 + 255) & ~255ull;
    int* schoice = (int*)(ws + chiB);
    int* perm    = (int*)(ws + 2 * chiB);
    u16* rp = (u16*)(ws + 3 * chiB);
    const size_t rpB = ((size_t)P.off[17] * 2 + 255) & ~255ull;
    const size_t RPB = 3 * chiB + rpB;

    // fixed region: fg_u (32*64*256 u32) + out_u (32*64*384 u32) = 5,242,880 B
    unsigned int* fg_u_all  = (unsigned int*)(ws + RPB);
    unsigned int* out_u_all = fg_u_all + 32 * 64 * 256;
    const size_t UB = 5242880ull;
    const int nU = 32 * 64 * 640;

    k_repack<<<dim3(1024), 256, 0, stream>>>(P, d_in[1], chi, rp, fg_u_all, nU);
    k_sort<<<dim3(P.chN >> 13), 256, 0, stream>>>(chi, schoice, perm);

    const u16* xyz  = rp + P.off[0];
    const u16* w1   = rp + P.off[1];
    const u16* b1   = rp + P.off[2];
    const u16* bn1g = rp + P.off[3];
    const u16* bn1b = rp + P.off[4];
    const u16* bn1m = rp + P.off[5];
    const u16* bn1v = rp + P.off[6];
    const u16* w2   = rp + P.off[7];
    const u16* b2   = rp + P.off[8];
    const u16* w3   = rp + P.off[9];
    const u16* b3   = rp + P.off[10];
    const u16* bn2g = rp + P.off[11];
    const u16* bn2b = rp + P.off[12];
    const u16* bn2m = rp + P.off[13];
    const u16* bn2v = rp + P.off[14];
    const u16* w4   = rp + P.off[15];
    const u16* b4   = rp + P.off[16];

    // per-batch: feat 4,194,304 + fg 32,768 = 4,227,072  (h2 eliminated by fusion)
    const size_t PB = 4227072ull;
    int sb = 32;
    while (sb > 1 && RPB + UB + (size_t)sb * PB > ws_size) sb >>= 1;
    if (RPB + UB + PB > ws_size) {
        k_fillf<<<dim3((out_size + 255) / 256), 256, 0, stream>>>(out, out_size, 3000.0f);
        return;
    }
    const int ns = 32 / sb;

    char* wsb = ws + RPB + UB;
    const size_t featB = (size_t)sb * 8192 * 256 * 2;
    u16* feat = (u16*)(wsb);
    u16* fg   = (u16*)(wsb + featB);

    const int mblk = sb << 6;        // 128-row M-tiles per slice
    const int nfg = sb * 64 * 256;
    const int nou = sb * 64 * 384;
    for (int s = 0; s < ns; ++s) {
        const int b0 = s * sb;
        const int pt0 = b0 << 13;
        const int* sch_sl = schoice + pt0;
        const int* perm_sl = perm + pt0;
        unsigned int* fg_u  = fg_u_all + (size_t)b0 * 64 * 256;
        unsigned int* out_u = out_u_all + (size_t)b0 * 64 * 384;
        g1_feat<<<dim3(mblk), 256, 0, stream>>>(xyz, w1, b1, bn1g, bn1b, bn1m, bn1v,
                                                w2, b2, sch_sl, perm_sl, feat, fg_u);
        k_dec_bf<<<dim3((nfg + 255) / 256), 256, 0, stream>>>(fg_u, fg, nfg);
        g34_out<<<dim3(mblk), 1024, 0, stream>>>(sch_sl, feat, fg, w3, b3,
                                                 bn2g, bn2b, bn2m, bn2v, w4, b4, out_u);
        k_dec_f32<<<dim3((nou + 255) / 256), 256, 0, stream>>>(out_u,
                                                               out + ((size_t)b0 << 6) * 384, nou);
    }
}